// Round 3
// baseline (63.559 us; speedup 1.0000x reference)
//
#include <hip/hip_runtime.h>

#define B_   4
#define NC_  128
#define NM_  16384
#define OUTROW 1700
#define FACTORF ((float)(27.2114 * 0.529177249))

__device__ __forceinline__ float fast_tanh(float x) {
    float e = __expf(2.0f * x);
    return 1.0f - 2.0f * __builtin_amdgcn_rcpf(e + 1.0f);
}
__device__ __forceinline__ unsigned short f2bf(float x) {
    unsigned u = __float_as_uint(x);
    return (unsigned short)((u + 0x7fffu + ((u >> 16) & 1u)) >> 16);
}
__device__ __forceinline__ float bflo(unsigned u) { return __uint_as_float(u << 16); }
__device__ __forceinline__ float bfhi(unsigned u) { return __uint_as_float(u & 0xffff0000u); }

// ---------------------------------------------------------------------------
// Kernel 0: detect byte-packed (bool) vs int32 mask.
__global__ __launch_bounds__(256) void k_detect(const uint4* __restrict__ mask,
                                                int* __restrict__ flag) {
    __shared__ int s;
    if (threadIdx.x == 0) s = 0;
    __syncthreads();
    int bad = 0;
    for (int i = threadIdx.x; i < NM_ / 4; i += 256) {
        uint4 v = mask[i];
        bad |= (v.x > 1u) | (v.y > 1u) | (v.z > 1u) | (v.w > 1u);
    }
    if (bad) atomicOr(&s, 1);
    __syncthreads();
    if (threadIdx.x == 0) *flag = s;
}

// ---------------------------------------------------------------------------
// Kernel 1: esp/efield partial sums. Block (b, chunk). Deterministic partials.
__global__ __launch_bounds__(256) void k_esp(
    const float* __restrict__ atom_coords, const float* __restrict__ charge_coords,
    const float* __restrict__ charges, const void* __restrict__ mask,
    const int* __restrict__ flagp, float4* __restrict__ partial, int nchunk)
{
    const int t  = threadIdx.x;
    const int b  = blockIdx.x / nchunk;
    const int ch = blockIdx.x % nchunk;
    const int chunkM = NM_ / nchunk;
    const int a = t & 127;
    const int h = t >> 7;
    const int byteMask = *flagp;

    __shared__ float4 stg[256];
    __shared__ float4 psum[128];

    float ax, ay, az;
    {
        const float* p = atom_coords + (size_t)(b * NC_ + a) * 3;
        ax = p[0]; ay = p[1]; az = p[2];
    }
    const float* ccb = charge_coords + (size_t)b * NM_ * 3;
    const float* chb = charges + (size_t)b * NM_;
    const unsigned char* mb8 = (const unsigned char*)mask + (size_t)b * NM_;
    const int* mb32 = (const int*)mask + (size_t)b * NM_;

    float s0 = 0.0f, s1 = 0.0f, s2 = 0.0f, s3 = 0.0f;

    for (int tb = 0; tb < chunkM; tb += 256) {
        int m = ch * chunkM + tb + t;
        float cx = ccb[3 * m + 0], cy = ccb[3 * m + 1], cz = ccb[3 * m + 2];
        int mk = byteMask ? (int)mb8[m] : mb32[m];
        float q = mk ? chb[m] : 0.0f;
        stg[t] = make_float4(cx, cy, cz, q);
        __syncthreads();
        const float4* sp = stg + h * 128;
#pragma unroll 8
        for (int i = 0; i < 128; ++i) {
            float4 cq = sp[i];
            float dx = ax - cq.x, dy = ay - cq.y, dz = az - cq.z;
            float d2 = dx * dx + dy * dy + dz * dz;
            float inv = __builtin_amdgcn_rsqf(d2);
            float inv3 = inv * inv * inv;
            float qi  = cq.w * inv;
            float qi3 = cq.w * inv3;
            s0 += qi;
            s1 += qi3 * dx; s2 += qi3 * dy; s3 += qi3 * dz;
        }
        __syncthreads();
    }
    if (h == 1) psum[a] = make_float4(s0, s1, s2, s3);
    __syncthreads();
    if (h == 0) {
        float4 o = psum[a];
        partial[(size_t)(b * NC_ + a) * nchunk + ch] =
            make_float4(s0 + o.x, s1 + o.y, s2 + o.z, s3 + o.w);
    }
}

// ---------------------------------------------------------------------------
// Kernel 2: partial reduction + esp MLP + ef MLP stack + Gram. Block (b,n).
// bf16 LDS for w1/y1 (occupancy), fused neuron-halves in P2, Gram via readlane.
__global__ __launch_bounds__(256, 3) void k_ef(
    const float* __restrict__ atom_coords, const float4* __restrict__ partial, int nchunk,
    const int* __restrict__ atom_types,
    const float* __restrict__ eW0, const float* __restrict__ eb0,
    const float* __restrict__ eW1, const float* __restrict__ eb1,
    const float* __restrict__ eW2, const float* __restrict__ eb2,
    const float* __restrict__ fW0, const float* __restrict__ fb0,
    const float* __restrict__ fW1, const float* __restrict__ fb1,
    const float* __restrict__ fW2, const float* __restrict__ fb2,
    float* __restrict__ out)
{
    const int t   = threadIdx.x;
    const int blk = blockIdx.x;
    const int b   = blk >> 7;
    const int n   = blk & 127;

    __shared__ float cst[NC_][3];
    __shared__ float proj[128];
    __shared__ int   cl[128];
    __shared__ int   sidx[128];
    __shared__ int   sc[128];
    __shared__ int   basep[8];
    __shared__ float a0s[6][25];
    __shared__ float b0s[6][25];
    __shared__ float b1s[6][50];
    __shared__ float b2s[6][100];
    __shared__ float espf[4];
    __shared__ float h0e[25];
    __shared__ float h1e[52];
    // union region: [w1b 6x50x28 u16 = 16800B][y1p 128x56 u16 = 14336B] = 31136B
    // overlaid by Gtmp [4][100][16] f32 = 25600B after P2.
    __shared__ __align__(16) char uni[31136];
    unsigned short (*w1b)[50][28] = (unsigned short (*)[50][28])uni;
    unsigned short (*y1p)[56]     = (unsigned short (*)[56])(uni + 16800);
    float (*Gtmp)[100][16]        = (float (*)[100][16])uni;

    const int tn = atom_types[n];
    const int c0 = tn * 6;

    // ---- stage ----
    for (int idx = t; idx < NC_ * 3; idx += 256)
        (&cst[0][0])[idx] = atom_coords[(size_t)b * NC_ * 3 + idx];
    for (int idx = t; idx < 150; idx += 256) {
        (&a0s[0][0])[idx] = fW0[c0 * 25 + idx];
        (&b0s[0][0])[idx] = fb0[c0 * 25 + idx];
    }
    for (int idx = t; idx < 300; idx += 256) (&b1s[0][0])[idx] = fb1[c0 * 50 + idx];
    for (int idx = t; idx < 600; idx += 256) (&b2s[0][0])[idx] = fb2[c0 * 100 + idx];
    for (int idx = t; idx < 7500; idx += 256) {
        int c_ = idx / 1250;
        int rem = idx - 1250 * c_;
        int k = rem / 25;
        int l = rem - 25 * k;
        w1b[c_][k][l] = f2bf(fW1[c0 * 1250 + idx]);
    }
    // ---- reduce chunk partials (wave 0) ----
    if (t < 64) {
        float4 v = make_float4(0.f, 0.f, 0.f, 0.f);
        if (t < nchunk) v = partial[(size_t)(b * NC_ + n) * nchunk + t];
#pragma unroll
        for (int off = 32; off > 0; off >>= 1) {
            v.x += __shfl_xor(v.x, off, 64);
            v.y += __shfl_xor(v.y, off, 64);
            v.z += __shfl_xor(v.z, off, 64);
            v.w += __shfl_xor(v.w, off, 64);
        }
        if (t == 0) {
            espf[0] = v.x * FACTORF;
            espf[1] = v.y * FACTORF;
            espf[2] = v.z * FACTORF;
            espf[3] = v.w * FACTORF;
        }
    }
    __syncthreads();

    // ---- phase A: proj+channel (t<127)  ||  esp layer0 (t in [128,153)) ----
    if (t < 127) {
        int jn = (t < n) ? t : t + 1;
        float rx = cst[n][0] - cst[jn][0];
        float ry = cst[n][1] - cst[jn][1];
        float rz = cst[n][2] - cst[jn][2];
        float d2 = rx * rx + ry * ry + rz * rz;
        proj[t] = (rx * espf[1] + ry * espf[2] + rz * espf[3]) / d2;
        cl[t] = atom_types[jn];
    } else if (t >= 128 && t < 153) {
        int l = t - 128;
        h0e[l] = fast_tanh(eW0[tn * 25 + l] * espf[0] + eb0[tn * 25 + l]);
    }
    __syncthreads();
    // ---- phase B: basep (t<7)  ||  esp layer1 (t in [128,178)) ----
    if (t < 7) {
        int s = 0;
        for (int j = 0; j < 127; ++j) s += (cl[j] < t) ? 1 : 0;
        basep[t] = s;
    } else if (t >= 128 && t < 178) {
        int l = t - 128;
        float s = eb1[tn * 50 + l];
        const float* wr = eW1 + (size_t)(tn * 50 + l) * 25;
#pragma unroll
        for (int j = 0; j < 25; ++j) s += wr[j] * h0e[j];
        h1e[l] = fast_tanh(s) + h0e[l % 25];
    }
    __syncthreads();
    // ---- phase C: stable sort scatter (t<127)  ||  esp layer2 (t in [128,228)) ----
    if (t < 127) {
        int myc = cl[t];
        int pos = basep[myc];
        for (int j = 0; j < t; ++j) pos += (cl[j] == myc) ? 1 : 0;
        sidx[pos] = t; sc[pos] = myc;
    } else if (t >= 128 && t < 228) {
        int k = t - 128;
        float s = eb2[tn * 100 + k];
        const float* wr = eW2 + (size_t)(tn * 100 + k) * 50;
#pragma unroll
        for (int j = 0; j < 50; ++j) s += wr[j] * h1e[j];
        out[(size_t)(b * NC_ + n) * OUTROW + k] = fast_tanh(s) + h1e[k % 50];
    }
    __syncthreads();

    // ---- P1: layer0 + layer1 for all 127 rows (2 threads per row), bf16 in/out
    {
        int r = t >> 1, h = t & 1;
        if (r < 127) {
            int c = sc[r];
            float x = proj[sidx[r]];
            float y0[25];
#pragma unroll
            for (int k = 0; k < 25; ++k) y0[k] = fast_tanh(a0s[c][k] * x + b0s[c][k]);
#pragma unroll
            for (int kk = 0; kk < 25; ++kk) {
                int k = h * 25 + kk;
                float s = b1s[c][k];
                const uint2* wp = (const uint2*)&w1b[c][k][0];
#pragma unroll
                for (int j = 0; j < 6; ++j) {
                    uint2 w = wp[j];
                    s += bflo(w.x) * y0[4 * j + 0] + bfhi(w.x) * y0[4 * j + 1]
                       + bflo(w.y) * y0[4 * j + 2] + bfhi(w.y) * y0[4 * j + 3];
                }
                s += bflo(((const unsigned*)&w1b[c][k][0])[12]) * y0[24];
                y1p[r][k] = f2bf(fast_tanh(s) + y0[kk]);
            }
        }
    }
    __syncthreads();

    // ---- P2: layer2 (fused neuron halves) + Gram via readlane.
    //      Lane L (Leff=min(L,49)) owns neurons Leff and Leff+50; waves split rows mod 4.
    const int wv = t >> 6;
    const int L  = t & 63;
    const int Leff = (L < 50) ? L : 49;
    float Glo[16], Ghi[16];
#pragma unroll
    for (int a = 0; a < 16; ++a) { Glo[a] = 0.0f; Ghi[a] = 0.0f; }
#pragma unroll 1
    for (int c = 0; c < 6; ++c) {
        const int pbeg = basep[c], pend = basep[c + 1];
        if (pbeg == pend) continue;
        float wlo[50], whi[50];
        {
            const float2* r0 = (const float2*)(fW2 + (size_t)((c0 + c) * 100 + Leff) * 50);
            const float2* r1 = (const float2*)(fW2 + (size_t)((c0 + c) * 100 + Leff + 50) * 50);
#pragma unroll
            for (int j = 0; j < 25; ++j) {
                float2 u = r0[j]; wlo[2 * j] = u.x; wlo[2 * j + 1] = u.y;
                float2 v = r1[j]; whi[2 * j] = v.x; whi[2 * j + 1] = v.y;
            }
        }
        const float bblo = b2s[c][Leff];
        const float bbhi = b2s[c][Leff + 50];
        for (int p = pbeg + wv; p < pend; p += 4) {
            const uint4* y4 = (const uint4*)&y1p[p][0];
            float slo = 0.0f, shi = 0.0f;
#pragma unroll
            for (int j = 0; j < 6; ++j) {
                uint4 v = y4[j];
                float ya = bflo(v.x), yb = bfhi(v.x), yc = bflo(v.y), yd = bfhi(v.y);
                float ye = bflo(v.z), yf = bfhi(v.z), yg = bflo(v.w), yh = bfhi(v.w);
                slo += wlo[8 * j + 0] * ya + wlo[8 * j + 1] * yb
                     + wlo[8 * j + 2] * yc + wlo[8 * j + 3] * yd
                     + wlo[8 * j + 4] * ye + wlo[8 * j + 5] * yf
                     + wlo[8 * j + 6] * yg + wlo[8 * j + 7] * yh;
                shi += whi[8 * j + 0] * ya + whi[8 * j + 1] * yb
                     + whi[8 * j + 2] * yc + whi[8 * j + 3] * yd
                     + whi[8 * j + 4] * ye + whi[8 * j + 5] * yf
                     + whi[8 * j + 6] * yg + whi[8 * j + 7] * yh;
            }
            {
                unsigned v = ((const unsigned*)&y1p[p][0])[24];   // l = 48,49
                slo += wlo[48] * bflo(v) + wlo[49] * bfhi(v);
                shi += whi[48] * bflo(v) + whi[49] * bfhi(v);
            }
            float yres = bflo((unsigned)y1p[p][Leff]);
            float y20 = fast_tanh(slo + bblo) + yres;
            float y21 = fast_tanh(shi + bbhi) + yres;
#pragma unroll
            for (int a = 0; a < 16; ++a) {
                float va = __uint_as_float(
                    __builtin_amdgcn_readlane(__float_as_uint(y20), a));
                Glo[a] += y20 * va;
                Ghi[a] += y21 * va;
            }
        }
    }
    __syncthreads();   // all P1/P2 uses of w1b/y1p done; safe to overlay Gtmp
    if (L < 50) {
#pragma unroll
        for (int a = 0; a < 16; ++a) {
            Gtmp[wv][L][a] = Glo[a];
            Gtmp[wv][L + 50][a] = Ghi[a];
        }
    }
    __syncthreads();
    float* orow = out + (size_t)(b * NC_ + n) * OUTROW + 100;
    for (int o = t; o < 1600; o += 256) {
        int k = o >> 4, a = o & 15;
        orow[o] = 2.0f * (Gtmp[0][k][a] + Gtmp[1][k][a] + Gtmp[2][k][a] + Gtmp[3][k][a]);
    }
}

// ---------------------------------------------------------------------------
extern "C" void kernel_launch(void* const* d_in, const int* in_sizes, int n_in,
                              void* d_out, int out_size, void* d_ws, size_t ws_size,
                              hipStream_t stream) {
    (void)in_sizes; (void)n_in; (void)out_size;
    const float* atom_coords   = (const float*)d_in[0];
    const float* charge_coords = (const float*)d_in[1];
    const float* charges       = (const float*)d_in[2];
    const float* eW0 = (const float*)d_in[3];
    const float* eb0 = (const float*)d_in[4];
    const float* eW1 = (const float*)d_in[5];
    const float* eb1 = (const float*)d_in[6];
    const float* eW2 = (const float*)d_in[7];
    const float* eb2 = (const float*)d_in[8];
    const float* fW0 = (const float*)d_in[9];
    const float* fb0 = (const float*)d_in[10];
    const float* fW1 = (const float*)d_in[11];
    const float* fb1 = (const float*)d_in[12];
    const float* fW2 = (const float*)d_in[13];
    const float* fb2 = (const float*)d_in[14];
    const int*   atom_types = (const int*)d_in[15];
    const void*  mask = d_in[16];
    float* out = (float*)d_out;

    // ws layout: [0..255] flag; [256..] float4 partials [B][NC][nchunk]
    int nchunk = 64;
    while (nchunk > 1 && (size_t)(256 + (size_t)B_ * NC_ * nchunk * 16) > ws_size)
        nchunk >>= 1;
    int*    flag    = (int*)d_ws;
    float4* partial = (float4*)((char*)d_ws + 256);

    k_detect<<<1, 256, 0, stream>>>((const uint4*)mask, flag);
    k_esp<<<B_ * nchunk, 256, 0, stream>>>(
        atom_coords, charge_coords, charges, mask, flag, partial, nchunk);
    k_ef<<<B_ * NC_, 256, 0, stream>>>(
        atom_coords, partial, nchunk, atom_types,
        eW0, eb0, eW1, eb1, eW2, eb2,
        fW0, fb0, fW1, fb1, fW2, fb2, out);
}

// Round 4
// 47.478 us; speedup vs baseline: 1.3387x; 1.3387x over previous
//
#include <hip/hip_runtime.h>

#define B_   4
#define NC_  128
#define NM_  16384
#define OUTROW 1700
#define FACTORF ((float)(27.2114 * 0.529177249))

typedef __attribute__((ext_vector_type(8))) short short8v;   // 8 x bf16 (4 VGPR)
typedef __attribute__((ext_vector_type(4))) float float4v;   // MFMA acc

__device__ __forceinline__ float fast_tanh(float x) {
    float e = __expf(2.0f * x);
    return 1.0f - 2.0f * __builtin_amdgcn_rcpf(e + 1.0f);
}
__device__ __forceinline__ unsigned short f2bf(float x) {
    unsigned u = __float_as_uint(x);
    return (unsigned short)((u + 0x7fffu + ((u >> 16) & 1u)) >> 16);
}
__device__ __forceinline__ float bflo(unsigned u) { return __uint_as_float(u << 16); }
__device__ __forceinline__ float bfhi(unsigned u) { return __uint_as_float(u & 0xffff0000u); }

union FragU { uint4 u4; unsigned u[4]; short8v s; };

// ---------------------------------------------------------------------------
// Kernel 1: esp/efield partial sums. Block (b, chunk). Deterministic partials.
// Mask byte-vs-int32 detection folded in (64KB-safe window per batch).
__global__ __launch_bounds__(256) void k_esp(
    const float* __restrict__ atom_coords, const float* __restrict__ charge_coords,
    const float* __restrict__ charges, const void* __restrict__ mask,
    float4* __restrict__ partial, int nchunk)
{
    const int t  = threadIdx.x;
    const int b  = blockIdx.x / nchunk;
    const int ch = blockIdx.x % nchunk;
    const int chunkM = NM_ / nchunk;
    const int a = t & 127;
    const int h = t >> 7;

    __shared__ float4 stg[256];
    __shared__ float4 psum[128];
    __shared__ int sdet;

    if (t == 0) sdet = 0;
    __syncthreads();
    if (t < 16) {
        const uint4* mw = (const uint4*)mask;
        uint4 v = mw[b * 1024 + t];   // words [b*4096, +64) — inside 64KB either way
        if ((v.x > 1u) | (v.y > 1u) | (v.z > 1u) | (v.w > 1u)) atomicOr(&sdet, 1);
    }
    __syncthreads();
    const int byteMask = sdet;

    float ax, ay, az;
    {
        const float* p = atom_coords + (size_t)(b * NC_ + a) * 3;
        ax = p[0]; ay = p[1]; az = p[2];
    }
    const float* ccb = charge_coords + (size_t)b * NM_ * 3;
    const float* chb = charges + (size_t)b * NM_;
    const unsigned char* mb8 = (const unsigned char*)mask + (size_t)b * NM_;
    const int* mb32 = (const int*)mask + (size_t)b * NM_;

    float s0 = 0.0f, s1 = 0.0f, s2 = 0.0f, s3 = 0.0f;

    for (int tb = 0; tb < chunkM; tb += 256) {
        int m = ch * chunkM + tb + t;
        float cx = ccb[3 * m + 0], cy = ccb[3 * m + 1], cz = ccb[3 * m + 2];
        int mk = byteMask ? (int)mb8[m] : mb32[m];
        float q = mk ? chb[m] : 0.0f;
        stg[t] = make_float4(cx, cy, cz, q);
        __syncthreads();
        const float4* sp = stg + h * 128;
#pragma unroll 8
        for (int i = 0; i < 128; ++i) {
            float4 cq = sp[i];
            float dx = ax - cq.x, dy = ay - cq.y, dz = az - cq.z;
            float d2 = dx * dx + dy * dy + dz * dz;
            float inv = __builtin_amdgcn_rsqf(d2);
            float inv3 = inv * inv * inv;
            s0 += cq.w * inv;
            float qi3 = cq.w * inv3;
            s1 += qi3 * dx; s2 += qi3 * dy; s3 += qi3 * dz;
        }
        __syncthreads();
    }
    if (h == 1) psum[a] = make_float4(s0, s1, s2, s3);
    __syncthreads();
    if (h == 0) {
        float4 o = psum[a];
        partial[(size_t)(b * NC_ + a) * nchunk + ch] =
            make_float4(s0 + o.x, s1 + o.y, s2 + o.z, s3 + o.w);
    }
}

// ---------------------------------------------------------------------------
// Kernel 2: reduce partials + esp MLP + ef MLP (layer2 via MFMA) + Gram (MFMA).
__global__ __launch_bounds__(256, 2) void k_ef(
    const float* __restrict__ atom_coords, const float4* __restrict__ partial, int nchunk,
    const int* __restrict__ atom_types,
    const float* __restrict__ eW0, const float* __restrict__ eb0,
    const float* __restrict__ eW1, const float* __restrict__ eb1,
    const float* __restrict__ eW2, const float* __restrict__ eb2,
    const float* __restrict__ fW0, const float* __restrict__ fb0,
    const float* __restrict__ fW1, const float* __restrict__ fb1,
    const float* __restrict__ fW2, const float* __restrict__ fb2,
    float* __restrict__ out)
{
    const int t   = threadIdx.x;
    const int blk = blockIdx.x;
    const int b   = blk >> 7;
    const int n   = blk & 127;

    __shared__ float cst[NC_][3];
    __shared__ float proj[128];
    __shared__ int   cl[128];
    __shared__ int   sidx[128];
    __shared__ int   sc[128];
    __shared__ int   basep[8];
    __shared__ int   tbase[16], tch[16];
    __shared__ int   tcnt;
    __shared__ float a0s[6][25];
    __shared__ float b0s[6][25];
    __shared__ float b1s[6][50];
    __shared__ float b2s[6][100];
    __shared__ float espf[4];
    __shared__ float h0e[25];
    __shared__ float h1e[52];
    __shared__ __align__(16) unsigned short w1b[6][50][28];   // 16800 B
    __shared__ __align__(16) unsigned short y1p[144][72];     // 20736 B (row 144B: 2-way banks, b128 ok)
    __shared__ __align__(16) unsigned short y2t[112][136];    // 30464 B (row 272B: 2-way banks)

    const int tn = atom_types[n];
    const int c0 = tn * 6;
    const int wv   = t >> 6;
    const int lane = t & 63;

    // ---- stage + zero pads ----
    for (int idx = t; idx < NC_ * 3; idx += 256)
        (&cst[0][0])[idx] = atom_coords[(size_t)b * NC_ * 3 + idx];
    for (int idx = t; idx < 150; idx += 256) {
        (&a0s[0][0])[idx] = fW0[c0 * 25 + idx];
        (&b0s[0][0])[idx] = fb0[c0 * 25 + idx];
    }
    for (int idx = t; idx < 300; idx += 256) (&b1s[0][0])[idx] = fb1[c0 * 50 + idx];
    for (int idx = t; idx < 600; idx += 256) (&b2s[0][0])[idx] = fb2[c0 * 100 + idx];
    for (int idx = t; idx < 7500; idx += 256) {
        int c_ = idx / 1250;
        int rem = idx - 1250 * c_;
        int k = rem / 25;
        int l = rem - 25 * k;
        w1b[c_][k][l] = f2bf(fW1[c0 * 1250 + idx]);
    }
    {
        uint4 z = make_uint4(0, 0, 0, 0);
        uint4* zp = (uint4*)&y1p[0][0];
        for (int i = t; i < 1296; i += 256) zp[i] = z;   // 144*72*2/16
        uint4* zq = (uint4*)&y2t[0][0];
        for (int i = t; i < 1904; i += 256) zq[i] = z;   // 112*136*2/16
    }
    // ---- reduce chunk partials (wave 0) ----
    if (t < 64) {
        float4 v = make_float4(0.f, 0.f, 0.f, 0.f);
        if (t < nchunk) v = partial[(size_t)(b * NC_ + n) * nchunk + t];
#pragma unroll
        for (int off = 32; off > 0; off >>= 1) {
            v.x += __shfl_xor(v.x, off, 64);
            v.y += __shfl_xor(v.y, off, 64);
            v.z += __shfl_xor(v.z, off, 64);
            v.w += __shfl_xor(v.w, off, 64);
        }
        if (t == 0) {
            espf[0] = v.x * FACTORF;
            espf[1] = v.y * FACTORF;
            espf[2] = v.z * FACTORF;
            espf[3] = v.w * FACTORF;
        }
    }
    __syncthreads();

    // ---- phase A: proj+channel (t<127)  ||  esp layer0 ----
    if (t < 127) {
        int jn = (t < n) ? t : t + 1;
        float rx = cst[n][0] - cst[jn][0];
        float ry = cst[n][1] - cst[jn][1];
        float rz = cst[n][2] - cst[jn][2];
        float d2 = rx * rx + ry * ry + rz * rz;
        proj[t] = (rx * espf[1] + ry * espf[2] + rz * espf[3]) / d2;
        cl[t] = atom_types[jn];
    } else if (t >= 128 && t < 153) {
        int l = t - 128;
        h0e[l] = fast_tanh(eW0[tn * 25 + l] * espf[0] + eb0[tn * 25 + l]);
    }
    __syncthreads();
    // ---- phase B: basep (t<7)  ||  esp layer1 ----
    if (t < 7) {
        int s = 0;
        for (int j = 0; j < 127; ++j) s += (cl[j] < t) ? 1 : 0;
        basep[t] = s;
    } else if (t >= 128 && t < 178) {
        int l = t - 128;
        float s = eb1[tn * 50 + l];
        const float* wr = eW1 + (size_t)(tn * 50 + l) * 25;
#pragma unroll
        for (int j = 0; j < 25; ++j) s += wr[j] * h0e[j];
        h1e[l] = fast_tanh(s) + h0e[l % 25];
    }
    __syncthreads();
    // ---- phase C: sort scatter (t<127) || esp layer2 (128..227) || tiles (t==240)
    if (t < 127) {
        int myc = cl[t];
        int pos = basep[myc];
        for (int j = 0; j < t; ++j) pos += (cl[j] == myc) ? 1 : 0;
        sidx[pos] = t; sc[pos] = myc;
    } else if (t >= 128 && t < 228) {
        int k = t - 128;
        float s = eb2[tn * 100 + k];
        const float* wr = eW2 + (size_t)(tn * 100 + k) * 50;
#pragma unroll
        for (int j = 0; j < 50; ++j) s += wr[j] * h1e[j];
        out[(size_t)(b * NC_ + n) * OUTROW + k] = fast_tanh(s) + h1e[k % 50];
    } else if (t == 240) {
        int nt = 0;
        for (int c = 0; c < 6; ++c)
            for (int base = basep[c]; base < basep[c + 1]; base += 16) {
                tbase[nt] = base; tch[nt] = c; ++nt;
            }
        tcnt = nt;
    }
    __syncthreads();

    // ---- P1: layer0 + layer1 for all 127 rows (2 threads/row), bf16 out ----
    {
        int r = t >> 1, h = t & 1;
        if (r < 127) {
            int c = sc[r];
            float x = proj[sidx[r]];
            float y0[25];
#pragma unroll
            for (int k = 0; k < 25; ++k) y0[k] = fast_tanh(a0s[c][k] * x + b0s[c][k]);
#pragma unroll
            for (int kk = 0; kk < 25; ++kk) {
                int k = h * 25 + kk;
                float s = b1s[c][k];
                const uint2* wp = (const uint2*)&w1b[c][k][0];
#pragma unroll
                for (int j = 0; j < 6; ++j) {
                    uint2 w = wp[j];
                    s += bflo(w.x) * y0[4 * j + 0] + bfhi(w.x) * y0[4 * j + 1]
                       + bflo(w.y) * y0[4 * j + 2] + bfhi(w.y) * y0[4 * j + 3];
                }
                s += bflo(((const unsigned*)&w1b[c][k][0])[12]) * y0[24];
                y1p[r][k] = f2bf(fast_tanh(s) + y0[kk]);
            }
        }
    }
    __syncthreads();

    // ---- GEMM1 (MFMA): Y2 = tanh(Y1 @ W2^T + b2) + res, stored transposed bf16.
    // Wave wv owns n-tiles {wv, wv+4}. All waves iterate all m-tiles.
    {
        const int nnt = (wv < 3) ? 2 : 1;
        short8v Bf0[2], Bf1[2];
        float bias[2];
        int nres[2], nnv[2];
#pragma unroll
        for (int q = 0; q < 2; ++q) {
            int nt = wv + 4 * q;
            nnv[q]  = nt * 16 + (lane & 15);
            nres[q] = nnv[q] % 50;
        }
        int ccur = -1;
        const int krow = (lane >> 4) << 3;   // 0,8,16,24
#pragma unroll 1
        for (int ti = 0; ti < tcnt; ++ti) {
            const int c = tch[ti], base = tbase[ti], pend = basep[c + 1];
            if (c != ccur) {
                ccur = c;
#pragma unroll
                for (int q = 0; q < 2; ++q) {
                    if (q >= nnt) break;
                    const int nn = nnv[q];
                    const bool nok = nn < 100;
                    const float* wbase = fW2 + ((size_t)(c0 + c) * 100 + (nok ? nn : 0)) * 50;
#pragma unroll
                    for (int ks = 0; ks < 2; ++ks) {
                        FragU cv;
#pragma unroll
                        for (int e2 = 0; e2 < 4; ++e2) {
                            int ka = ks * 32 + krow + 2 * e2;
                            int kb = ka + 1;
                            const float* pa = wbase + (ka < 50 ? ka : 0);
                            const float* pb = wbase + (kb < 50 ? kb : 0);
                            float fa = (nok && ka < 50) ? *pa : 0.0f;
                            float fb = (nok && kb < 50) ? *pb : 0.0f;
                            cv.u[e2] = (unsigned)f2bf(fa) | ((unsigned)f2bf(fb) << 16);
                        }
                        if (ks == 0) Bf0[q] = cv.s; else Bf1[q] = cv.s;
                    }
                    bias[q] = nok ? b2s[c][nn] : 0.0f;
                }
            }
            // A fragments: rows base+(lane&15), k = ks*32 + krow + [0..7]
            FragU A0, A1;
            const int ar = base + (lane & 15);
            A0.u4 = *(const uint4*)&y1p[ar][krow];
            A1.u4 = *(const uint4*)&y1p[ar][32 + krow];
#pragma unroll
            for (int q = 0; q < 2; ++q) {
                if (q >= nnt) break;
                float4v acc = {0.f, 0.f, 0.f, 0.f};
                acc = __builtin_amdgcn_mfma_f32_16x16x32_bf16(A0.s, Bf0[q], acc, 0, 0, 0);
                acc = __builtin_amdgcn_mfma_f32_16x16x32_bf16(A1.s, Bf1[q], acc, 0, 0, 0);
                const int nn = nnv[q];
                if (nn < 100) {
                    const int prow = base + ((lane >> 4) << 2);
#pragma unroll
                    for (int r = 0; r < 4; ++r) {
                        int p = prow + r;
                        if (p < pend) {
                            float yres = bflo((unsigned)y1p[p][nres[q]]);
                            float y2 = fast_tanh(acc[r] + bias[q]) + yres;
                            y2t[nn][p] = f2bf(y2);
                        }
                    }
                }
            }
        }
    }
    __syncthreads();

    // ---- Gram (MFMA): G[m][a] = sum_p Y2T[m][p] * Y2T[a][p]; K = 128 (row 127 zero).
    {
        const int krow = (lane >> 4) << 3;
        short8v GB[4];
#pragma unroll
        for (int ks = 0; ks < 4; ++ks) {
            FragU cv; cv.u4 = *(const uint4*)&y2t[lane & 15][ks * 32 + krow];
            GB[ks] = cv.s;
        }
        float* orow = out + (size_t)(b * NC_ + n) * OUTROW + 100;
        const int aa = lane & 15;
#pragma unroll
        for (int q = 0; q < 2; ++q) {
            const int mt = wv + 4 * q;
            if (mt >= 7) break;
            const int m0 = mt * 16 + (lane & 15);
            float4v acc = {0.f, 0.f, 0.f, 0.f};
#pragma unroll
            for (int ks = 0; ks < 4; ++ks) {
                FragU av; av.u4 = *(const uint4*)&y2t[m0][ks * 32 + krow];
                acc = __builtin_amdgcn_mfma_f32_16x16x32_bf16(av.s, GB[ks], acc, 0, 0, 0);
            }
            const int mrow = mt * 16 + ((lane >> 4) << 2);
#pragma unroll
            for (int r = 0; r < 4; ++r) {
                int m = mrow + r;
                if (m < 100) orow[m * 16 + aa] = 2.0f * acc[r];
            }
        }
    }
}

// ---------------------------------------------------------------------------
extern "C" void kernel_launch(void* const* d_in, const int* in_sizes, int n_in,
                              void* d_out, int out_size, void* d_ws, size_t ws_size,
                              hipStream_t stream) {
    (void)in_sizes; (void)n_in; (void)out_size;
    const float* atom_coords   = (const float*)d_in[0];
    const float* charge_coords = (const float*)d_in[1];
    const float* charges       = (const float*)d_in[2];
    const float* eW0 = (const float*)d_in[3];
    const float* eb0 = (const float*)d_in[4];
    const float* eW1 = (const float*)d_in[5];
    const float* eb1 = (const float*)d_in[6];
    const float* eW2 = (const float*)d_in[7];
    const float* eb2 = (const float*)d_in[8];
    const float* fW0 = (const float*)d_in[9];
    const float* fb0 = (const float*)d_in[10];
    const float* fW1 = (const float*)d_in[11];
    const float* fb1 = (const float*)d_in[12];
    const float* fW2 = (const float*)d_in[13];
    const float* fb2 = (const float*)d_in[14];
    const int*   atom_types = (const int*)d_in[15];
    const void*  mask = d_in[16];
    float* out = (float*)d_out;

    // ws: float4 partials [B][NC][nchunk]
    int nchunk = 64;
    while (nchunk > 1 && (size_t)((size_t)B_ * NC_ * nchunk * 16) > ws_size)
        nchunk >>= 1;
    float4* partial = (float4*)d_ws;

    k_esp<<<B_ * nchunk, 256, 0, stream>>>(
        atom_coords, charge_coords, charges, mask, partial, nchunk);
    k_ef<<<B_ * NC_, 256, 0, stream>>>(
        atom_coords, partial, nchunk, atom_types,
        eW0, eb0, eW1, eb1, eW2, eb2,
        fW0, fb0, fW1, fb1, fW2, fb2, out);
}

// Round 5
// 45.634 us; speedup vs baseline: 1.3928x; 1.0404x over previous
//
#include <hip/hip_runtime.h>

#define B_   4
#define NC_  128
#define NM_  16384
#define OUTROW 1700
#define FACTORF ((float)(27.2114 * 0.529177249))

typedef __attribute__((ext_vector_type(8))) short short8v;   // 8 x bf16 (4 VGPR)
typedef __attribute__((ext_vector_type(4))) float float4v;   // MFMA acc

__device__ __forceinline__ float fast_tanh(float x) {
    float e = __expf(2.0f * x);
    return 1.0f - 2.0f * __builtin_amdgcn_rcpf(e + 1.0f);
}
__device__ __forceinline__ unsigned short f2bf(float x) {
    unsigned u = __float_as_uint(x);
    return (unsigned short)((u + 0x7fffu + ((u >> 16) & 1u)) >> 16);
}
__device__ __forceinline__ float bflo(unsigned u) { return __uint_as_float(u << 16); }

union FragU { uint4 u4; unsigned u[4]; short8v s; };

// ---------------------------------------------------------------------------
// Kernel 0: prepack fW1 -> w1bf[36][64][32] bf16 (rows=50 neurons pad64,
// cols=25 pad32, zero-padded), fW2 -> w2bf[36][112][64] bf16 (rows=100 pad112,
// cols=50 pad64, zero-padded). Fragment-ready A-operand layouts.
__global__ __launch_bounds__(256) void k_pack(
    const float* __restrict__ fW1, const float* __restrict__ fW2,
    unsigned short* __restrict__ w1bf, unsigned short* __restrict__ w2bf)
{
    const int blk = blockIdx.x, t = threadIdx.x;
    if (blk < 36) {
        unsigned short* dst = w1bf + blk * 2048;
        const float* src = fW1 + blk * 1250;
        for (int i = t; i < 2048; i += 256) {
            int k = i >> 5, l = i & 31;
            float v = (k < 50 && l < 25) ? src[k * 25 + l] : 0.0f;
            dst[i] = f2bf(v);
        }
    } else {
        int cp = blk - 36;
        unsigned short* dst = w2bf + cp * 7168;
        const float* src = fW2 + cp * 5000;
        for (int i = t; i < 7168; i += 256) {
            int nn = i >> 6, kk = i & 63;
            float v = (nn < 100 && kk < 50) ? src[nn * 50 + kk] : 0.0f;
            dst[i] = f2bf(v);
        }
    }
}

// ---------------------------------------------------------------------------
// Kernel 1: esp/efield partial sums. Block (b, chunk); 128-charge tiles.
__global__ __launch_bounds__(256) void k_esp(
    const float* __restrict__ atom_coords, const float* __restrict__ charge_coords,
    const float* __restrict__ charges, const void* __restrict__ mask,
    float4* __restrict__ partial, int nchunk)
{
    const int t  = threadIdx.x;
    const int b  = blockIdx.x / nchunk;
    const int ch = blockIdx.x % nchunk;
    const int chunkM = NM_ / nchunk;
    const int a = t & 127;
    const int h = t >> 7;

    __shared__ float4 stg[128];
    __shared__ float4 psum[128];
    __shared__ int sdet;

    if (t == 0) sdet = 0;
    __syncthreads();
    if (t < 16) {
        const uint4* mw = (const uint4*)mask;
        uint4 v = mw[b * 1024 + t];   // 256B window, in-bounds either layout
        if ((v.x > 1u) | (v.y > 1u) | (v.z > 1u) | (v.w > 1u)) atomicOr(&sdet, 1);
    }
    __syncthreads();
    const int byteMask = sdet;

    float ax, ay, az;
    {
        const float* p = atom_coords + (size_t)(b * NC_ + a) * 3;
        ax = p[0]; ay = p[1]; az = p[2];
    }
    const float* ccb = charge_coords + (size_t)b * NM_ * 3;
    const float* chb = charges + (size_t)b * NM_;
    const unsigned char* mb8 = (const unsigned char*)mask + (size_t)b * NM_;
    const int* mb32 = (const int*)mask + (size_t)b * NM_;

    float s0 = 0.0f, s1 = 0.0f, s2 = 0.0f, s3 = 0.0f;

    for (int tb = 0; tb < chunkM; tb += 128) {
        if (t < 128) {
            int m = ch * chunkM + tb + t;
            float cx = ccb[3 * m + 0], cy = ccb[3 * m + 1], cz = ccb[3 * m + 2];
            int mk = byteMask ? (int)mb8[m] : mb32[m];
            float q = mk ? chb[m] : 0.0f;
            stg[t] = make_float4(cx, cy, cz, q);
        }
        __syncthreads();
        const float4* sp = stg + h * 64;
#pragma unroll 8
        for (int i = 0; i < 64; ++i) {
            float4 cq = sp[i];
            float dx = ax - cq.x, dy = ay - cq.y, dz = az - cq.z;
            float d2 = dx * dx + dy * dy + dz * dz;
            float inv = __builtin_amdgcn_rsqf(d2);
            float inv3 = inv * inv * inv;
            s0 += cq.w * inv;
            float qi3 = cq.w * inv3;
            s1 += qi3 * dx; s2 += qi3 * dy; s3 += qi3 * dz;
        }
        __syncthreads();
    }
    if (h == 1) psum[a] = make_float4(s0, s1, s2, s3);
    __syncthreads();
    if (h == 0) {
        float4 o = psum[a];
        partial[(size_t)(b * NC_ + a) * nchunk + ch] =
            make_float4(s0 + o.x, s1 + o.y, s2 + o.z, s3 + o.w);
    }
}

// ---------------------------------------------------------------------------
// Kernel 2: reduce partials + esp MLP + ef MLP (all layers MFMA) + Gram (MFMA).
__global__ __launch_bounds__(256, 2) void k_ef(
    const float* __restrict__ atom_coords, const float4* __restrict__ partial, int nchunk,
    const int* __restrict__ atom_types,
    const float* __restrict__ eW0, const float* __restrict__ eb0,
    const float* __restrict__ eW1, const float* __restrict__ eb1,
    const float* __restrict__ eW2, const float* __restrict__ eb2,
    const float* __restrict__ fW0, const float* __restrict__ fb0,
    const float* __restrict__ fb1, const float* __restrict__ fb2,
    const unsigned short* __restrict__ w1bf, const unsigned short* __restrict__ w2bf,
    float* __restrict__ out)
{
    const int t   = threadIdx.x;
    const int blk = blockIdx.x;
    const int b   = blk >> 7;
    const int n   = blk & 127;

    __shared__ float cst[NC_][3];
    __shared__ float proj[128];
    __shared__ int   cl[128];
    __shared__ int   sidx[128];
    __shared__ int   sc[128];
    __shared__ int   basep[8];
    __shared__ int   tbase[16], tch[16];
    __shared__ int   tcnt;
    __shared__ float a0s[6][25];
    __shared__ float b0s[6][25];
    __shared__ float b1s[6][50];
    __shared__ float b2s[6][100];
    __shared__ float espf[4];
    __shared__ float h0e[25];
    __shared__ float h1e[52];
    __shared__ __align__(16) unsigned short y0p[144][32];    //  9216 B
    __shared__ __align__(16) unsigned short y1p[144][72];    // 20736 B
    __shared__ __align__(16) unsigned short y2t[112][136];   // 30464 B

    const int tn = atom_types[n];
    const int c0 = tn * 6;
    const int wv   = t >> 6;
    const int lane = t & 63;

    // ---- stage + y2t K-pad zero + reduce partials ----
    for (int idx = t; idx < NC_ * 3; idx += 256)
        (&cst[0][0])[idx] = atom_coords[(size_t)b * NC_ * 3 + idx];
    for (int idx = t; idx < 150; idx += 256) {
        (&a0s[0][0])[idx] = fW0[c0 * 25 + idx];
        (&b0s[0][0])[idx] = fb0[c0 * 25 + idx];
    }
    for (int idx = t; idx < 300; idx += 256) (&b1s[0][0])[idx] = fb1[c0 * 50 + idx];
    for (int idx = t; idx < 600; idx += 256) (&b2s[0][0])[idx] = fb2[c0 * 100 + idx];
    if (t < 112) y2t[t][127] = 0;
    if (t >= 128 && t < 192) {
        int lt = t - 128;
        float4 v = make_float4(0.f, 0.f, 0.f, 0.f);
        for (int ch = lt; ch < nchunk; ch += 64) {
            float4 u = partial[(size_t)(b * NC_ + n) * nchunk + ch];
            v.x += u.x; v.y += u.y; v.z += u.z; v.w += u.w;
        }
#pragma unroll
        for (int off = 32; off > 0; off >>= 1) {
            v.x += __shfl_xor(v.x, off, 64);
            v.y += __shfl_xor(v.y, off, 64);
            v.z += __shfl_xor(v.z, off, 64);
            v.w += __shfl_xor(v.w, off, 64);
        }
        if (lt == 0) {
            espf[0] = v.x * FACTORF;
            espf[1] = v.y * FACTORF;
            espf[2] = v.z * FACTORF;
            espf[3] = v.w * FACTORF;
        }
    }
    __syncthreads();

    // ---- phase A: proj+channel (t<127)  ||  esp layer0 ----
    if (t < 127) {
        int jn = (t < n) ? t : t + 1;
        float rx = cst[n][0] - cst[jn][0];
        float ry = cst[n][1] - cst[jn][1];
        float rz = cst[n][2] - cst[jn][2];
        float d2 = rx * rx + ry * ry + rz * rz;
        proj[t] = (rx * espf[1] + ry * espf[2] + rz * espf[3]) / d2;
        cl[t] = atom_types[jn];
    } else if (t >= 128 && t < 153) {
        int l = t - 128;
        h0e[l] = fast_tanh(eW0[tn * 25 + l] * espf[0] + eb0[tn * 25 + l]);
    }
    __syncthreads();
    // ---- phase B: basep (t<7)  ||  esp layer1 ----
    if (t < 7) {
        int s = 0;
        for (int j = 0; j < 127; ++j) s += (cl[j] < t) ? 1 : 0;
        basep[t] = s;
    } else if (t >= 128 && t < 178) {
        int l = t - 128;
        float s = eb1[tn * 50 + l];
        const float* wr = eW1 + (size_t)(tn * 50 + l) * 25;
#pragma unroll
        for (int j = 0; j < 25; ++j) s += wr[j] * h0e[j];
        h1e[l] = fast_tanh(s) + h0e[l % 25];
    }
    __syncthreads();
    // ---- phase C: sort (t<127) || esp layer2 (128..227) || tiles (t==240) ----
    if (t < 127) {
        int myc = cl[t];
        int pos = basep[myc];
        for (int j = 0; j < t; ++j) pos += (cl[j] == myc) ? 1 : 0;
        sidx[pos] = t; sc[pos] = myc;
    } else if (t >= 128 && t < 228) {
        int k = t - 128;
        float s = eb2[tn * 100 + k];
        const float* wr = eW2 + (size_t)(tn * 100 + k) * 50;
#pragma unroll
        for (int j = 0; j < 50; ++j) s += wr[j] * h1e[j];
        out[(size_t)(b * NC_ + n) * OUTROW + k] = fast_tanh(s) + h1e[k % 50];
    } else if (t == 240) {
        int nt = 0;
        for (int c = 0; c < 6; ++c)
            for (int base = basep[c]; base < basep[c + 1]; base += 16) {
                tbase[nt] = base; tch[nt] = c; ++nt;
            }
        tcnt = nt;
    }
    __syncthreads();

    // ---- Y0: y0p[r][l] = tanh(a0*x + b0), cols 25..31 zeroed (NaN hygiene) ----
    for (int i = t; i < 127 * 32; i += 256) {
        int r = i >> 5, l = i & 31;
        int c = sc[r];
        float x = proj[sidx[r]];
        float v = (l < 25) ? fast_tanh(a0s[c][l] * x + b0s[c][l]) : 0.0f;
        y0p[r][l] = f2bf(v);
    }
    __syncthreads();

    // ---- L1 (MFMA): Y1[p][k] = tanh(W1[k]·Y0[p] + b1[k]) + Y0[p][k%25].
    //      Wave wv owns neuron-rows wv*16..+15 (tile 3 = rows 48..63, zero pad).
    {
        const int krow = (lane >> 4) << 3;
        const int arow = wv * 16 + (lane & 15);
        int ccur = -1;
        FragU Af;
#pragma unroll 1
        for (int ti = 0; ti < tcnt; ++ti) {
            const int c = tch[ti], base = tbase[ti], pend = basep[c + 1];
            if (c != ccur) {
                ccur = c;
                Af.u4 = *(const uint4*)(w1bf + ((size_t)(c0 + c) * 64 + arow) * 32 + krow);
            }
            FragU Bf;
            Bf.u4 = *(const uint4*)&y0p[base + (lane & 15)][krow];
            float4v acc = {0.f, 0.f, 0.f, 0.f};
            acc = __builtin_amdgcn_mfma_f32_16x16x32_bf16(Af.s, Bf.s, acc, 0, 0, 0);
            const int p = base + (lane & 15);
            if (p < pend) {
                const int kb = wv * 16 + ((lane >> 4) << 2);
                unsigned short yv[4];
#pragma unroll
                for (int r = 0; r < 4; ++r) {
                    int k = kb + r;
                    float s = acc[r] + ((k < 50) ? b1s[c][k] : 0.0f);
                    float y = fast_tanh(s);
                    if (k < 50) y += bflo((unsigned)y0p[p][k % 25]);
                    yv[r] = f2bf(y);
                }
                unsigned lo = (unsigned)yv[0] | ((unsigned)yv[1] << 16);
                unsigned hi = (unsigned)yv[2] | ((unsigned)yv[3] << 16);
                *(uint2*)&y1p[p][kb] = make_uint2(lo, hi);
            }
        }
    }
    __syncthreads();

    // ---- L2 (MFMA): Y2T[nn][p] = tanh(W2[nn]·Y1[p] + b2[nn]) + Y1[p][nn%50].
    //      Wave wv owns nn-tiles {wv, wv+4} of 7.
    {
        const int krow = (lane >> 4) << 3;
        const int nnt = (wv < 3) ? 2 : 1;
        FragU Af[2][2];
        int ccur = -1;
#pragma unroll 1
        for (int ti = 0; ti < tcnt; ++ti) {
            const int c = tch[ti], base = tbase[ti], pend = basep[c + 1];
            if (c != ccur) {
                ccur = c;
#pragma unroll
                for (int q = 0; q < 2; ++q) {
                    if (q >= nnt) break;
                    const int arow = (wv + 4 * q) * 16 + (lane & 15);
                    const unsigned short* wb =
                        w2bf + ((size_t)(c0 + c) * 112 + arow) * 64;
                    Af[q][0].u4 = *(const uint4*)(wb + krow);
                    Af[q][1].u4 = *(const uint4*)(wb + 32 + krow);
                }
            }
            FragU B0, B1;
            const int p = base + (lane & 15);
            B0.u4 = *(const uint4*)&y1p[p][krow];
            B1.u4 = *(const uint4*)&y1p[p][32 + krow];
#pragma unroll
            for (int q = 0; q < 2; ++q) {
                if (q >= nnt) break;
                float4v acc = {0.f, 0.f, 0.f, 0.f};
                acc = __builtin_amdgcn_mfma_f32_16x16x32_bf16(Af[q][0].s, B0.s, acc, 0, 0, 0);
                acc = __builtin_amdgcn_mfma_f32_16x16x32_bf16(Af[q][1].s, B1.s, acc, 0, 0, 0);
                if (p < pend) {
                    const int nb = (wv + 4 * q) * 16 + ((lane >> 4) << 2);
#pragma unroll
                    for (int r = 0; r < 4; ++r) {
                        int nn = nb + r;
                        if (nn < 100) {
                            float yres = bflo((unsigned)y1p[p][nn % 50]);
                            float y2 = fast_tanh(acc[r] + b2s[c][nn]) + yres;
                            y2t[nn][p] = f2bf(y2);
                        }
                    }
                }
            }
        }
    }
    __syncthreads();

    // ---- Gram (MFMA): G[m][a] = sum_p Y2T[m][p]*Y2T[a][p]; K=128 (col 127 = 0).
    {
        const int krow = (lane >> 4) << 3;
        short8v GB[4];
#pragma unroll
        for (int ks = 0; ks < 4; ++ks) {
            FragU cv; cv.u4 = *(const uint4*)&y2t[lane & 15][ks * 32 + krow];
            GB[ks] = cv.s;
        }
        float* orow = out + (size_t)(b * NC_ + n) * OUTROW + 100;
        const int aa = lane & 15;
#pragma unroll
        for (int q = 0; q < 2; ++q) {
            const int mt = wv + 4 * q;
            if (mt >= 7) break;
            const int m0 = mt * 16 + (lane & 15);
            float4v acc = {0.f, 0.f, 0.f, 0.f};
#pragma unroll
            for (int ks = 0; ks < 4; ++ks) {
                FragU av; av.u4 = *(const uint4*)&y2t[m0][ks * 32 + krow];
                acc = __builtin_amdgcn_mfma_f32_16x16x32_bf16(av.s, GB[ks], acc, 0, 0, 0);
            }
            const int mrow = mt * 16 + ((lane >> 4) << 2);
#pragma unroll
            for (int r = 0; r < 4; ++r) {
                int m = mrow + r;
                if (m < 100) orow[m * 16 + aa] = 2.0f * acc[r];
            }
        }
    }
}

// ---------------------------------------------------------------------------
extern "C" void kernel_launch(void* const* d_in, const int* in_sizes, int n_in,
                              void* d_out, int out_size, void* d_ws, size_t ws_size,
                              hipStream_t stream) {
    (void)in_sizes; (void)n_in; (void)out_size;
    const float* atom_coords   = (const float*)d_in[0];
    const float* charge_coords = (const float*)d_in[1];
    const float* charges       = (const float*)d_in[2];
    const float* eW0 = (const float*)d_in[3];
    const float* eb0 = (const float*)d_in[4];
    const float* eW1 = (const float*)d_in[5];
    const float* eb1 = (const float*)d_in[6];
    const float* eW2 = (const float*)d_in[7];
    const float* eb2 = (const float*)d_in[8];
    const float* fW0 = (const float*)d_in[9];
    const float* fb0 = (const float*)d_in[10];
    const float* fW1 = (const float*)d_in[11];
    const float* fb1 = (const float*)d_in[12];
    const float* fW2 = (const float*)d_in[13];
    const float* fb2 = (const float*)d_in[14];
    const int*   atom_types = (const int*)d_in[15];
    const void*  mask = d_in[16];
    float* out = (float*)d_out;

    // ws layout: [w1bf 147456B][w2bf 516096B][partial B*NC*nchunk*16]
    const size_t W1BF_B = 36 * 64 * 32 * 2;     // 147456
    const size_t W2BF_B = 36 * 112 * 64 * 2;    // 516096
    unsigned short* w1bf = (unsigned short*)d_ws;
    unsigned short* w2bf = (unsigned short*)((char*)d_ws + W1BF_B);
    float4* partial = (float4*)((char*)d_ws + W1BF_B + W2BF_B);

    int nchunk = 128;
    while (nchunk > 1 &&
           W1BF_B + W2BF_B + (size_t)B_ * NC_ * nchunk * 16 > ws_size)
        nchunk >>= 1;

    k_pack<<<72, 256, 0, stream>>>(fW1, fW2, w1bf, w2bf);
    k_esp<<<B_ * nchunk, 256, 0, stream>>>(
        atom_coords, charge_coords, charges, mask, partial, nchunk);
    k_ef<<<B_ * NC_, 256, 0, stream>>>(
        atom_coords, partial, nchunk, atom_types,
        eW0, eb0, eW1, eb1, eW2, eb2,
        fW0, fb0, fb1, fb2, w1bf, w2bf, out);
}

// Round 6
// 39.656 us; speedup vs baseline: 1.6027x; 1.1507x over previous
//
#include <hip/hip_runtime.h>

#define B_   4
#define NC_  128
#define NM_  16384
#define OUTROW 1700
#define FACTORF ((float)(27.2114 * 0.529177249))

typedef __attribute__((ext_vector_type(8))) short short8v;   // 8 x bf16 (4 VGPR)
typedef __attribute__((ext_vector_type(4))) float float4v;   // MFMA acc

__device__ __forceinline__ float fast_tanh(float x) {
    float e = __expf(2.0f * x);
    return 1.0f - 2.0f * __builtin_amdgcn_rcpf(e + 1.0f);
}
__device__ __forceinline__ unsigned short f2bf(float x) {
    unsigned u = __float_as_uint(x);
    return (unsigned short)((u + 0x7fffu + ((u >> 16) & 1u)) >> 16);
}
__device__ __forceinline__ float bflo(unsigned u) { return __uint_as_float(u << 16); }

union FragU { uint4 u4; unsigned u[4]; short8v s; };

// ---------------------------------------------------------------------------
// Kernel 0: fused weight-prepack (blocks 0..71) + esp/efield partials (72..).
__global__ __launch_bounds__(256) void k_prep(
    const float* __restrict__ fW1, const float* __restrict__ fW2,
    unsigned short* __restrict__ w1bf, unsigned short* __restrict__ w2bf,
    const float* __restrict__ atom_coords, const float* __restrict__ charge_coords,
    const float* __restrict__ charges, const void* __restrict__ mask,
    float4* __restrict__ partial, int nchunk)
{
    const int t = threadIdx.x;
    const int blk = blockIdx.x;
    if (blk < 36) {
        unsigned short* dst = w1bf + blk * 2048;
        const float* src = fW1 + blk * 1250;
        for (int i = t; i < 2048; i += 256) {
            int k = i >> 5, l = i & 31;
            float v = (k < 50 && l < 25) ? src[k * 25 + l] : 0.0f;
            dst[i] = f2bf(v);
        }
        return;
    }
    if (blk < 72) {
        int cp = blk - 36;
        unsigned short* dst = w2bf + cp * 7168;
        const float* src = fW2 + cp * 5000;
        for (int i = t; i < 7168; i += 256) {
            int nn = i >> 6, kk = i & 63;
            float v = (nn < 100 && kk < 50) ? src[nn * 50 + kk] : 0.0f;
            dst[i] = f2bf(v);
        }
        return;
    }
    // ---- esp part ----
    const int eb = blk - 72;
    const int b  = eb / nchunk;
    const int ch = eb % nchunk;
    const int chunkM = NM_ / nchunk;
    const int a = t & 127;
    const int h = t >> 7;

    __shared__ float4 stg[128];
    __shared__ float4 psum[128];
    __shared__ int sdet;

    if (t == 0) sdet = 0;
    __syncthreads();
    if (t < 16) {
        const uint4* mw = (const uint4*)mask;
        uint4 v = mw[b * 1024 + t];   // 256B window, in-bounds either layout
        if ((v.x > 1u) | (v.y > 1u) | (v.z > 1u) | (v.w > 1u)) atomicOr(&sdet, 1);
    }
    __syncthreads();
    const int byteMask = sdet;

    float ax, ay, az;
    {
        const float* p = atom_coords + (size_t)(b * NC_ + a) * 3;
        ax = p[0]; ay = p[1]; az = p[2];
    }
    const float* ccb = charge_coords + (size_t)b * NM_ * 3;
    const float* chb = charges + (size_t)b * NM_;
    const unsigned char* mb8 = (const unsigned char*)mask + (size_t)b * NM_;
    const int* mb32 = (const int*)mask + (size_t)b * NM_;

    float s0 = 0.0f, s1 = 0.0f, s2 = 0.0f, s3 = 0.0f;

    for (int tb = 0; tb < chunkM; tb += 128) {
        if (t < 128) {
            int m = ch * chunkM + tb + t;
            float cx = ccb[3 * m + 0], cy = ccb[3 * m + 1], cz = ccb[3 * m + 2];
            int mk = byteMask ? (int)mb8[m] : mb32[m];
            float q = mk ? chb[m] : 0.0f;
            stg[t] = make_float4(cx, cy, cz, q);
        }
        __syncthreads();
        const float4* sp = stg + h * 64;
#pragma unroll 8
        for (int i = 0; i < 64; ++i) {
            float4 cq = sp[i];
            float dx = ax - cq.x, dy = ay - cq.y, dz = az - cq.z;
            float d2 = dx * dx + dy * dy + dz * dz;
            float inv = __builtin_amdgcn_rsqf(d2);
            float inv3 = inv * inv * inv;
            s0 += cq.w * inv;
            float qi3 = cq.w * inv3;
            s1 += qi3 * dx; s2 += qi3 * dy; s3 += qi3 * dz;
        }
        __syncthreads();
    }
    if (h == 1) psum[a] = make_float4(s0, s1, s2, s3);
    __syncthreads();
    if (h == 0) {
        float4 o = psum[a];
        partial[(size_t)(b * NC_ + a) * nchunk + ch] =
            make_float4(s0 + o.x, s1 + o.y, s2 + o.z, s3 + o.w);
    }
}

// ---------------------------------------------------------------------------
// Kernel 1: reduce partials + esp MLP + ef MLP (MFMA) + Gram (MFMA).
// Ballot-sort (O(1)), register tile-list, prefetched W-fragments.
__global__ __launch_bounds__(256, 2) void k_ef(
    const float* __restrict__ atom_coords, const float4* __restrict__ partial, int nchunk,
    const int* __restrict__ atom_types,
    const float* __restrict__ eW0, const float* __restrict__ eb0,
    const float* __restrict__ eW1, const float* __restrict__ eb1,
    const float* __restrict__ eW2, const float* __restrict__ eb2,
    const float* __restrict__ fW0, const float* __restrict__ fb0,
    const float* __restrict__ fb1, const float* __restrict__ fb2,
    const unsigned short* __restrict__ w1bf, const unsigned short* __restrict__ w2bf,
    float* __restrict__ out)
{
    const int t   = threadIdx.x;
    const int blk = blockIdx.x;
    const int b   = blk >> 7;
    const int n   = blk & 127;

    __shared__ float cst[NC_][3];
    __shared__ float xs[128];
    __shared__ int   sc[128];
    __shared__ int   tat[128];
    __shared__ int   basep[8];
    __shared__ int   wcnt[2][6];
    __shared__ int   tbase[16], tch[16];
    __shared__ int   tcnt;
    __shared__ float a0s[6][25];
    __shared__ float b0s[6][25];
    __shared__ float b1s[6][50];
    __shared__ float b2s[6][100];
    __shared__ float espf[4];
    __shared__ float h0e[25];
    __shared__ float h1e[52];
    __shared__ __align__(16) unsigned short y0p[128][32];    //  8192 B
    __shared__ __align__(16) unsigned short y1p[128][72];    // 18432 B
    __shared__ __align__(16) unsigned short y2t[112][136];   // 30464 B

    const int tn = atom_types[n];
    const int c0 = tn * 6;
    const int wv   = t >> 6;
    const int lane = t & 63;

    // ---- stage + pads + partial reduce ----
    for (int idx = t; idx < NC_ * 3; idx += 256)
        (&cst[0][0])[idx] = atom_coords[(size_t)b * NC_ * 3 + idx];
    if (t < 128) tat[t] = atom_types[t];
    for (int idx = t; idx < 150; idx += 256) {
        (&a0s[0][0])[idx] = fW0[c0 * 25 + idx];
        (&b0s[0][0])[idx] = fb0[c0 * 25 + idx];
    }
    for (int idx = t; idx < 300; idx += 256) (&b1s[0][0])[idx] = fb1[c0 * 50 + idx];
    for (int idx = t; idx < 600; idx += 256) (&b2s[0][0])[idx] = fb2[c0 * 100 + idx];
    if (t < 112) y2t[t][127] = 0;
    if (t >= 128 && t < 192) {
        int lt = t - 128;
        float4 v = make_float4(0.f, 0.f, 0.f, 0.f);
        for (int ch = lt; ch < nchunk; ch += 64) {
            float4 u = partial[(size_t)(b * NC_ + n) * nchunk + ch];
            v.x += u.x; v.y += u.y; v.z += u.z; v.w += u.w;
        }
#pragma unroll
        for (int off = 32; off > 0; off >>= 1) {
            v.x += __shfl_xor(v.x, off, 64);
            v.y += __shfl_xor(v.y, off, 64);
            v.z += __shfl_xor(v.z, off, 64);
            v.w += __shfl_xor(v.w, off, 64);
        }
        if (lt == 0) {
            espf[0] = v.x * FACTORF;
            espf[1] = v.y * FACTORF;
            espf[2] = v.z * FACTORF;
            espf[3] = v.w * FACTORF;
        }
    }
    __syncthreads();

    // ---- phase A: proj + channel + per-wave ballots (waves 0-1) || esp L0 ----
    unsigned long long mkeep = 0;
    int myc = 0; float px = 0.0f;
    if (wv < 2) {
        const bool valid = t < 127;
        if (valid) {
            int jn = (t < n) ? t : t + 1;
            float rx = cst[n][0] - cst[jn][0];
            float ry = cst[n][1] - cst[jn][1];
            float rz = cst[n][2] - cst[jn][2];
            float d2 = rx * rx + ry * ry + rz * rz;
            px = (rx * espf[1] + ry * espf[2] + rz * espf[3]) / d2;
            myc = tat[jn];
        }
#pragma unroll
        for (int v = 0; v < 6; ++v) {
            unsigned long long m = __ballot(valid && (myc == v));
            if (valid && myc == v) mkeep = m;
            if (lane == 0) wcnt[wv][v] = __builtin_popcountll(m);
        }
    } else if (t >= 128 && t < 153) {
        int l = t - 128;
        h0e[l] = fast_tanh(eW0[tn * 25 + l] * espf[0] + eb0[tn * 25 + l]);
    }
    __syncthreads();

    // ---- phase B: O(1) stable-sort scatter + basep + tile list || esp L1 ----
    if (t < 127) {
        int w0[6], w1[6];
#pragma unroll
        for (int v = 0; v < 6; ++v) { w0[v] = wcnt[0][v]; w1[v] = wcnt[1][v]; }
        int basec = 0;
#pragma unroll
        for (int v = 0; v < 6; ++v) if (v < myc) basec += w0[v] + w1[v];
        int pos = basec + (wv == 1 ? w0[myc] : 0)
                + __builtin_popcountll(mkeep & ((1ull << lane) - 1ull));
        sc[pos] = myc; xs[pos] = px;
        if (t == 0) {
            int run = 0, nt = 0;
#pragma unroll
            for (int v = 0; v < 6; ++v) {
                basep[v] = run;
                int cnt = w0[v] + w1[v];
                for (int base = run; base < run + cnt; base += 16) {
                    tbase[nt] = base; tch[nt] = v; ++nt;
                }
                run += cnt;
            }
            basep[6] = run;
            tcnt = nt;
        }
    } else if (t >= 128 && t < 178) {
        int l = t - 128;
        float s = eb1[tn * 50 + l];
        const float* wr = eW1 + (size_t)(tn * 50 + l) * 25;
#pragma unroll
        for (int j = 0; j < 25; ++j) s += wr[j] * h0e[j];
        h1e[l] = fast_tanh(s) + h0e[l % 25];
    }
    __syncthreads();

    // ---- phase C: Y0 (t<128) || esp L2 -> out (128..227) ----
    if (t < 128) {
        for (int i = t; i < 127 * 32; i += 128) {
            int r = i >> 5, l = i & 31;
            int c = sc[r]; float x = xs[r];
            float v = (l < 25) ? fast_tanh(a0s[c][l] * x + b0s[c][l]) : 0.0f;
            y0p[r][l] = f2bf(v);
        }
    } else if (t < 228) {
        int k = t - 128;
        float s = eb2[tn * 100 + k];
        const float2* wr = (const float2*)(eW2 + (size_t)(tn * 100 + k) * 50);
#pragma unroll
        for (int j = 0; j < 25; ++j) {
            float2 u = wr[j];
            s += u.x * h1e[2 * j] + u.y * h1e[2 * j + 1];
        }
        out[(size_t)(b * NC_ + n) * OUTROW + k] = fast_tanh(s) + h1e[k % 50];
    }
    __syncthreads();

    // ---- L1 (MFMA): Y1 = tanh(W1·Y0 + b1) + res; wave wv owns k-rows wv*16..+15
    {
        const int krow = (lane >> 4) << 3;
        const int arow = wv * 16 + (lane & 15);
        const unsigned short* wb = w1bf + ((size_t)c0 * 64 + arow) * 32 + krow;
        const int nt = tcnt;
        int c_cur = tch[0];
        int pend = basep[c_cur + 1];
        FragU Af, AfN;
        Af.u4 = *(const uint4*)(wb + (size_t)c_cur * 2048);
        int pendN = 0;
#pragma unroll 1
        for (int ti = 0; ti < nt; ++ti) {
            const int base = tbase[ti];
            const int c = c_cur;
            int cnext = (ti + 1 < nt) ? tch[ti + 1] : c;
            if (cnext != c) {
                AfN.u4 = *(const uint4*)(wb + (size_t)cnext * 2048);
                pendN = basep[cnext + 1];
            }
            FragU Bf;
            Bf.u4 = *(const uint4*)&y0p[base + (lane & 15)][krow];
            float4v acc = {0.f, 0.f, 0.f, 0.f};
            acc = __builtin_amdgcn_mfma_f32_16x16x32_bf16(Af.s, Bf.s, acc, 0, 0, 0);
            const int p = base + (lane & 15);
            if (p < pend) {
                const int kb = wv * 16 + ((lane >> 4) << 2);
                unsigned short yv[4];
#pragma unroll
                for (int r = 0; r < 4; ++r) {
                    int k = kb + r;
                    float s = acc[r] + ((k < 50) ? b1s[c][k] : 0.0f);
                    float y = fast_tanh(s);
                    if (k < 50) y += bflo((unsigned)y0p[p][k % 25]);
                    yv[r] = f2bf(y);
                }
                unsigned lo = (unsigned)yv[0] | ((unsigned)yv[1] << 16);
                unsigned hi = (unsigned)yv[2] | ((unsigned)yv[3] << 16);
                *(uint2*)&y1p[p][kb] = make_uint2(lo, hi);
            }
            if (cnext != c) { Af = AfN; pend = pendN; }
            c_cur = cnext;
        }
    }
    __syncthreads();

    // ---- L2 (MFMA): Y2T[nn][p] = tanh(W2[nn]·Y1[p] + b2) + res; waves own
    //      nn-tiles {wv, wv+4} of 7; next-channel fragments prefetched.
    {
        const int krow = (lane >> 4) << 3;
        const int nnt = (wv < 3) ? 2 : 1;
        const int nt = tcnt;
        int c_cur = tch[0];
        int pend = basep[c_cur + 1];
        FragU Af[2][2], AfN[2][2];
        int pendN = 0;
#pragma unroll
        for (int q = 0; q < 2; ++q) {
            if (q >= nnt) break;
            const int arow = (wv + 4 * q) * 16 + (lane & 15);
            const unsigned short* wb =
                w2bf + ((size_t)(c0 + c_cur) * 112 + arow) * 64;
            Af[q][0].u4 = *(const uint4*)(wb + krow);
            Af[q][1].u4 = *(const uint4*)(wb + 32 + krow);
        }
#pragma unroll 1
        for (int ti = 0; ti < nt; ++ti) {
            const int base = tbase[ti];
            const int c = c_cur;
            int cnext = (ti + 1 < nt) ? tch[ti + 1] : c;
            if (cnext != c) {
#pragma unroll
                for (int q = 0; q < 2; ++q) {
                    if (q >= nnt) break;
                    const int arow = (wv + 4 * q) * 16 + (lane & 15);
                    const unsigned short* wb =
                        w2bf + ((size_t)(c0 + cnext) * 112 + arow) * 64;
                    AfN[q][0].u4 = *(const uint4*)(wb + krow);
                    AfN[q][1].u4 = *(const uint4*)(wb + 32 + krow);
                }
                pendN = basep[cnext + 1];
            }
            FragU B0, B1;
            const int p = base + (lane & 15);
            B0.u4 = *(const uint4*)&y1p[p][krow];
            B1.u4 = *(const uint4*)&y1p[p][32 + krow];
#pragma unroll
            for (int q = 0; q < 2; ++q) {
                if (q >= nnt) break;
                float4v acc = {0.f, 0.f, 0.f, 0.f};
                acc = __builtin_amdgcn_mfma_f32_16x16x32_bf16(Af[q][0].s, B0.s, acc, 0, 0, 0);
                acc = __builtin_amdgcn_mfma_f32_16x16x32_bf16(Af[q][1].s, B1.s, acc, 0, 0, 0);
                if (p < pend) {
                    const int nb = (wv + 4 * q) * 16 + ((lane >> 4) << 2);
#pragma unroll
                    for (int r = 0; r < 4; ++r) {
                        int nn = nb + r;
                        if (nn < 100) {
                            float yres = bflo((unsigned)y1p[p][nn % 50]);
                            float y2 = fast_tanh(acc[r] + b2s[c][nn]) + yres;
                            y2t[nn][p] = f2bf(y2);
                        }
                    }
                }
            }
            if (cnext != c) {
#pragma unroll
                for (int q = 0; q < 2; ++q) {
                    if (q >= nnt) break;
                    Af[q][0] = AfN[q][0]; Af[q][1] = AfN[q][1];
                }
                pend = pendN;
            }
            c_cur = cnext;
        }
    }
    __syncthreads();

    // ---- Gram (MFMA): G[m][a] = sum_p Y2T[m][p]*Y2T[a][p]; K=128 (col 127 = 0)
    {
        const int krow = (lane >> 4) << 3;
        short8v GB[4];
#pragma unroll
        for (int ks = 0; ks < 4; ++ks) {
            FragU cv; cv.u4 = *(const uint4*)&y2t[lane & 15][ks * 32 + krow];
            GB[ks] = cv.s;
        }
        float* orow = out + (size_t)(b * NC_ + n) * OUTROW + 100;
        const int aa = lane & 15;
#pragma unroll
        for (int q = 0; q < 2; ++q) {
            const int mt = wv + 4 * q;
            if (mt >= 7) break;
            const int m0 = mt * 16 + (lane & 15);
            float4v acc = {0.f, 0.f, 0.f, 0.f};
#pragma unroll
            for (int ks = 0; ks < 4; ++ks) {
                FragU av; av.u4 = *(const uint4*)&y2t[m0][ks * 32 + krow];
                acc = __builtin_amdgcn_mfma_f32_16x16x32_bf16(av.s, GB[ks], acc, 0, 0, 0);
            }
            const int mrow = mt * 16 + ((lane >> 4) << 2);
#pragma unroll
            for (int r = 0; r < 4; ++r) {
                int m = mrow + r;
                if (m < 100) orow[m * 16 + aa] = 2.0f * acc[r];
            }
        }
    }
}

// ---------------------------------------------------------------------------
extern "C" void kernel_launch(void* const* d_in, const int* in_sizes, int n_in,
                              void* d_out, int out_size, void* d_ws, size_t ws_size,
                              hipStream_t stream) {
    (void)in_sizes; (void)n_in; (void)out_size;
    const float* atom_coords   = (const float*)d_in[0];
    const float* charge_coords = (const float*)d_in[1];
    const float* charges       = (const float*)d_in[2];
    const float* eW0 = (const float*)d_in[3];
    const float* eb0 = (const float*)d_in[4];
    const float* eW1 = (const float*)d_in[5];
    const float* eb1 = (const float*)d_in[6];
    const float* eW2 = (const float*)d_in[7];
    const float* eb2 = (const float*)d_in[8];
    const float* fW0 = (const float*)d_in[9];
    const float* fb0 = (const float*)d_in[10];
    const float* fW1 = (const float*)d_in[11];
    const float* fb1 = (const float*)d_in[12];
    const float* fW2 = (const float*)d_in[13];
    const float* fb2 = (const float*)d_in[14];
    const int*   atom_types = (const int*)d_in[15];
    const void*  mask = d_in[16];
    float* out = (float*)d_out;

    // ws layout: [w1bf 147456B][w2bf 516096B][partial B*NC*nchunk*16]
    const size_t W1BF_B = 36 * 64 * 32 * 2;     // 147456
    const size_t W2BF_B = 36 * 112 * 64 * 2;    // 516096
    unsigned short* w1bf = (unsigned short*)d_ws;
    unsigned short* w2bf = (unsigned short*)((char*)d_ws + W1BF_B);
    float4* partial = (float4*)((char*)d_ws + W1BF_B + W2BF_B);

    int nchunk = 128;
    while (nchunk > 1 &&
           W1BF_B + W2BF_B + (size_t)B_ * NC_ * nchunk * 16 > ws_size)
        nchunk >>= 1;

    k_prep<<<72 + B_ * nchunk, 256, 0, stream>>>(
        fW1, fW2, w1bf, w2bf,
        atom_coords, charge_coords, charges, mask, partial, nchunk);
    k_ef<<<B_ * NC_, 256, 0, stream>>>(
        atom_coords, partial, nchunk, atom_types,
        eW0, eb0, eW1, eb1, eW2, eb2,
        fW0, fb0, fb1, fb2, w1bf, w2bf, out);
}

// Round 7
// 32.000 us; speedup vs baseline: 1.9862x; 1.2393x over previous
//
#include <hip/hip_runtime.h>

#define B_   4
#define NC_  128
#define NM_  16384
#define OUTROW 1700
#define FACTORF ((float)(27.2114 * 0.529177249))

typedef __attribute__((ext_vector_type(8))) short short8v;   // 8 x bf16 (4 VGPR)
typedef __attribute__((ext_vector_type(4))) float float4v;   // MFMA acc

__device__ __forceinline__ float fast_tanh(float x) {
    float e = __expf(2.0f * x);
    return 1.0f - 2.0f * __builtin_amdgcn_rcpf(e + 1.0f);
}
__device__ __forceinline__ unsigned short f2bf(float x) {
    unsigned u = __float_as_uint(x);
    return (unsigned short)((u + 0x7fffu + ((u >> 16) & 1u)) >> 16);
}
__device__ __forceinline__ float bflo(unsigned u) { return __uint_as_float(u << 16); }

union FragU { uint4 u4; unsigned u[4]; short8v s; };

// ---------------------------------------------------------------------------
// Kernel 0: fused weight-prepack (blocks 0..71) + esp/efield partials (72..).
__global__ __launch_bounds__(256) void k_prep(
    const float* __restrict__ fW1, const float* __restrict__ fW2,
    unsigned short* __restrict__ w1bf, unsigned short* __restrict__ w2bf,
    const float* __restrict__ atom_coords, const float* __restrict__ charge_coords,
    const float* __restrict__ charges, const void* __restrict__ mask,
    float4* __restrict__ partial, int nchunk)
{
    const int t = threadIdx.x;
    const int blk = blockIdx.x;
    if (blk < 36) {
        unsigned short* dst = w1bf + blk * 2048;
        const float* src = fW1 + blk * 1250;
        for (int i = t; i < 2048; i += 256) {
            int k = i >> 5, l = i & 31;
            float v = (k < 50 && l < 25) ? src[k * 25 + l] : 0.0f;
            dst[i] = f2bf(v);
        }
        return;
    }
    if (blk < 72) {
        int cp = blk - 36;
        unsigned short* dst = w2bf + cp * 7168;
        const float* src = fW2 + cp * 5000;
        for (int i = t; i < 7168; i += 256) {
            int nn = i >> 6, kk = i & 63;
            float v = (nn < 100 && kk < 50) ? src[nn * 50 + kk] : 0.0f;
            dst[i] = f2bf(v);
        }
        return;
    }
    // ---- esp part ----
    const int eb = blk - 72;
    const int b  = eb / nchunk;
    const int ch = eb % nchunk;
    const int chunkM = NM_ / nchunk;
    const int a = t & 127;
    const int h = t >> 7;

    __shared__ float4 stg[128];
    __shared__ float4 psum[128];
    __shared__ int sdet;

    if (t == 0) sdet = 0;
    __syncthreads();
    if (t < 16) {
        const uint4* mw = (const uint4*)mask;
        uint4 v = mw[b * 1024 + t];   // 256B window, in-bounds either layout
        if ((v.x > 1u) | (v.y > 1u) | (v.z > 1u) | (v.w > 1u)) atomicOr(&sdet, 1);
    }
    __syncthreads();
    const int byteMask = sdet;

    float ax, ay, az;
    {
        const float* p = atom_coords + (size_t)(b * NC_ + a) * 3;
        ax = p[0]; ay = p[1]; az = p[2];
    }
    const float* ccb = charge_coords + (size_t)b * NM_ * 3;
    const float* chb = charges + (size_t)b * NM_;
    const unsigned char* mb8 = (const unsigned char*)mask + (size_t)b * NM_;
    const int* mb32 = (const int*)mask + (size_t)b * NM_;

    float s0 = 0.0f, s1 = 0.0f, s2 = 0.0f, s3 = 0.0f;

    for (int tb = 0; tb < chunkM; tb += 128) {
        if (t < 128) {
            int m = ch * chunkM + tb + t;
            float cx = ccb[3 * m + 0], cy = ccb[3 * m + 1], cz = ccb[3 * m + 2];
            int mk = byteMask ? (int)mb8[m] : mb32[m];
            float q = mk ? chb[m] : 0.0f;
            stg[t] = make_float4(cx, cy, cz, q);
        }
        __syncthreads();
        const float4* sp = stg + h * 64;
#pragma unroll 8
        for (int i = 0; i < 64; ++i) {
            float4 cq = sp[i];
            float dx = ax - cq.x, dy = ay - cq.y, dz = az - cq.z;
            float d2 = dx * dx + dy * dy + dz * dz;
            float inv = __builtin_amdgcn_rsqf(d2);
            float inv3 = inv * inv * inv;
            s0 += cq.w * inv;
            float qi3 = cq.w * inv3;
            s1 += qi3 * dx; s2 += qi3 * dy; s3 += qi3 * dz;
        }
        __syncthreads();
    }
    if (h == 1) psum[a] = make_float4(s0, s1, s2, s3);
    __syncthreads();
    if (h == 0) {
        float4 o = psum[a];
        partial[(size_t)(b * NC_ + a) * nchunk + ch] =
            make_float4(s0 + o.x, s1 + o.y, s2 + o.z, s3 + o.w);
    }
}

// ---------------------------------------------------------------------------
// Kernel 1: reduce partials + esp MLP + ef MLP (MFMA) + Gram (MFMA).
// 512 threads = 8 waves: L2 nn-tiles 1/wave, L1 split 8 ways, 16 waves/CU.
__global__ __launch_bounds__(512, 4) void k_ef(
    const float* __restrict__ atom_coords, const float4* __restrict__ partial, int nchunk,
    const int* __restrict__ atom_types,
    const float* __restrict__ eW0, const float* __restrict__ eb0,
    const float* __restrict__ eW1, const float* __restrict__ eb1,
    const float* __restrict__ eW2, const float* __restrict__ eb2,
    const float* __restrict__ fW0, const float* __restrict__ fb0,
    const float* __restrict__ fb1, const float* __restrict__ fb2,
    const unsigned short* __restrict__ w1bf, const unsigned short* __restrict__ w2bf,
    float* __restrict__ out)
{
    const int t   = threadIdx.x;
    const int blk = blockIdx.x;
    const int b   = blk >> 7;
    const int n   = blk & 127;

    __shared__ float cst[NC_][3];
    __shared__ float xs[128];
    __shared__ int   sc[128];
    __shared__ int   tat[128];
    __shared__ int   basep[8];
    __shared__ int   wcnt[2][6];
    __shared__ int   tbase[16], tch[16];
    __shared__ int   tcnt;
    __shared__ float a0s[6][25];
    __shared__ float b0s[6][25];
    __shared__ float b1s[6][50];
    __shared__ float b2s[6][100];
    __shared__ float espf[4];
    __shared__ float h0e[25];
    __shared__ float h1e[52];
    __shared__ __align__(16) unsigned short y0p[128][32];    //  8192 B
    __shared__ __align__(16) unsigned short y1p[128][72];    // 18432 B
    __shared__ __align__(16) unsigned short y2t[112][136];   // 30464 B

    const int tn = atom_types[n];
    const int c0 = tn * 6;
    const int wv   = t >> 6;
    const int lane = t & 63;

    // ---- stage + pads + partial reduce (wave 4) ----
    for (int idx = t; idx < NC_ * 3; idx += 512)
        (&cst[0][0])[idx] = atom_coords[(size_t)b * NC_ * 3 + idx];
    if (t < 128) tat[t] = atom_types[t];
    for (int idx = t; idx < 150; idx += 512) {
        (&a0s[0][0])[idx] = fW0[c0 * 25 + idx];
        (&b0s[0][0])[idx] = fb0[c0 * 25 + idx];
    }
    if (t >= 192 && t < 492) (&b1s[0][0])[t - 192] = fb1[c0 * 50 + t - 192];
    if (t < 128) y2t[t][127] = 0;
    if (t >= 128 && t < 192) {
        // b2s via 64 threads x ~9 each
        for (int idx = t - 128; idx < 600; idx += 64)
            (&b2s[0][0])[idx] = fb2[c0 * 100 + idx];
    }
    if (t >= 256 && t < 320) {
        int lt = t - 256;
        float4 v = make_float4(0.f, 0.f, 0.f, 0.f);
        for (int ch = lt; ch < nchunk; ch += 64) {
            float4 u = partial[(size_t)(b * NC_ + n) * nchunk + ch];
            v.x += u.x; v.y += u.y; v.z += u.z; v.w += u.w;
        }
#pragma unroll
        for (int off = 32; off > 0; off >>= 1) {
            v.x += __shfl_xor(v.x, off, 64);
            v.y += __shfl_xor(v.y, off, 64);
            v.z += __shfl_xor(v.z, off, 64);
            v.w += __shfl_xor(v.w, off, 64);
        }
        if (lt == 0) {
            espf[0] = v.x * FACTORF;
            espf[1] = v.y * FACTORF;
            espf[2] = v.z * FACTORF;
            espf[3] = v.w * FACTORF;
        }
    }
    __syncthreads();

    // ---- phase A: proj + channel + ballots (waves 0-1) || esp L0 ----
    unsigned long long mkeep = 0;
    int myc = 0; float px = 0.0f;
    if (wv < 2) {
        const bool valid = t < 127;
        if (valid) {
            int jn = (t < n) ? t : t + 1;
            float rx = cst[n][0] - cst[jn][0];
            float ry = cst[n][1] - cst[jn][1];
            float rz = cst[n][2] - cst[jn][2];
            float d2 = rx * rx + ry * ry + rz * rz;
            px = (rx * espf[1] + ry * espf[2] + rz * espf[3]) / d2;
            myc = tat[jn];
        }
#pragma unroll
        for (int v = 0; v < 6; ++v) {
            unsigned long long m = __ballot(valid && (myc == v));
            if (valid && myc == v) mkeep = m;
            if (lane == 0) wcnt[wv][v] = __builtin_popcountll(m);
        }
    } else if (t >= 320 && t < 345) {
        int l = t - 320;
        h0e[l] = fast_tanh(eW0[tn * 25 + l] * espf[0] + eb0[tn * 25 + l]);
    }
    __syncthreads();

    // ---- phase B: O(1) scatter + basep + tile list || esp L1 ----
    if (t < 127) {
        int w0[6], w1[6];
#pragma unroll
        for (int v = 0; v < 6; ++v) { w0[v] = wcnt[0][v]; w1[v] = wcnt[1][v]; }
        int basec = 0;
#pragma unroll
        for (int v = 0; v < 6; ++v) if (v < myc) basec += w0[v] + w1[v];
        int pos = basec + (wv == 1 ? w0[myc] : 0)
                + __builtin_popcountll(mkeep & ((1ull << lane) - 1ull));
        sc[pos] = myc; xs[pos] = px;
        if (t == 0) {
            int run = 0, nt = 0;
#pragma unroll
            for (int v = 0; v < 6; ++v) {
                basep[v] = run;
                int cnt = w0[v] + w1[v];
                for (int base = run; base < run + cnt; base += 16) {
                    tbase[nt] = base; tch[nt] = v; ++nt;
                }
                run += cnt;
            }
            basep[6] = run;
            tcnt = nt;
        }
    } else if (t >= 320 && t < 370) {
        int l = t - 320;
        float s = eb1[tn * 50 + l];
        const float* wr = eW1 + (size_t)(tn * 50 + l) * 25;
#pragma unroll
        for (int j = 0; j < 25; ++j) s += wr[j] * h0e[j];
        h1e[l] = fast_tanh(s) + h0e[l % 25];
    }
    __syncthreads();

    // ---- phase C: Y0 (waves 0-3) || esp L2 -> out (t in [320,420)) ----
    if (t < 256) {
        for (int i = t; i < 127 * 32; i += 256) {
            int r = i >> 5, l = i & 31;
            int c = sc[r]; float x = xs[r];
            float v = (l < 25) ? fast_tanh(a0s[c][l] * x + b0s[c][l]) : 0.0f;
            y0p[r][l] = f2bf(v);
        }
    } else if (t >= 320 && t < 420) {
        int k = t - 320;
        float s = eb2[tn * 100 + k];
        const float2* wr = (const float2*)(eW2 + (size_t)(tn * 100 + k) * 50);
#pragma unroll
        for (int j = 0; j < 25; ++j) {
            float2 u = wr[j];
            s += u.x * h1e[2 * j] + u.y * h1e[2 * j + 1];
        }
        out[(size_t)(b * NC_ + n) * OUTROW + k] = fast_tanh(s) + h1e[k % 50];
    }
    __syncthreads();

    // ---- L1 (MFMA): Y1 = tanh(W1·Y0 + b1) + res.
    //      Wave wv: neuron-tile wv&3, row-tiles (wv>>2)::2. ----
    {
        const int kt = wv & 3;
        const int krow = (lane >> 4) << 3;
        const int arow = kt * 16 + (lane & 15);
        const unsigned short* wb = w1bf + ((size_t)c0 * 64 + arow) * 32 + krow;
        int ccur = -1;
        FragU Af;
        const int nt = tcnt;
#pragma unroll 1
        for (int ti = (wv >> 2); ti < nt; ti += 2) {
            const int c = tch[ti], base = tbase[ti], pend = basep[c + 1];
            if (c != ccur) {
                ccur = c;
                Af.u4 = *(const uint4*)(wb + (size_t)c * 2048);
            }
            FragU Bf;
            Bf.u4 = *(const uint4*)&y0p[base + (lane & 15)][krow];
            float4v acc = {0.f, 0.f, 0.f, 0.f};
            acc = __builtin_amdgcn_mfma_f32_16x16x32_bf16(Af.s, Bf.s, acc, 0, 0, 0);
            const int p = base + (lane & 15);
            if (p < pend) {
                const int kb = kt * 16 + ((lane >> 4) << 2);
                unsigned short yv[4];
#pragma unroll
                for (int r = 0; r < 4; ++r) {
                    int k = kb + r;
                    float s = acc[r] + ((k < 50) ? b1s[c][k] : 0.0f);
                    float y = fast_tanh(s);
                    if (k < 50) y += bflo((unsigned)y0p[p][k % 25]);
                    yv[r] = f2bf(y);
                }
                unsigned lo = (unsigned)yv[0] | ((unsigned)yv[1] << 16);
                unsigned hi = (unsigned)yv[2] | ((unsigned)yv[3] << 16);
                *(uint2*)&y1p[p][kb] = make_uint2(lo, hi);
            }
        }
    }
    __syncthreads();

    // ---- L2 (MFMA): Y2T[nn][p] = tanh(W2[nn]·Y1[p] + b2) + res.
    //      Wave wv (<7) owns nn-tile wv; iterates all row-tiles. ----
    if (wv < 7) {
        const int krow = (lane >> 4) << 3;
        const int arow = wv * 16 + (lane & 15);
        int ccur = -1;
        FragU A0, A1;
        const int nt = tcnt;
#pragma unroll 1
        for (int ti = 0; ti < nt; ++ti) {
            const int c = tch[ti], base = tbase[ti], pend = basep[c + 1];
            if (c != ccur) {
                ccur = c;
                const unsigned short* wb =
                    w2bf + ((size_t)(c0 + c) * 112 + arow) * 64;
                A0.u4 = *(const uint4*)(wb + krow);
                A1.u4 = *(const uint4*)(wb + 32 + krow);
            }
            FragU B0, B1;
            const int p = base + (lane & 15);
            B0.u4 = *(const uint4*)&y1p[p][krow];
            B1.u4 = *(const uint4*)&y1p[p][32 + krow];
            float4v acc = {0.f, 0.f, 0.f, 0.f};
            acc = __builtin_amdgcn_mfma_f32_16x16x32_bf16(A0.s, B0.s, acc, 0, 0, 0);
            acc = __builtin_amdgcn_mfma_f32_16x16x32_bf16(A1.s, B1.s, acc, 0, 0, 0);
            if (p < pend) {
                const int nb = wv * 16 + ((lane >> 4) << 2);
#pragma unroll
                for (int r = 0; r < 4; ++r) {
                    int nn = nb + r;
                    if (nn < 100) {
                        float yres = bflo((unsigned)y1p[p][nn % 50]);
                        float y2 = fast_tanh(acc[r] + b2s[c][nn]) + yres;
                        y2t[nn][p] = f2bf(y2);
                    }
                }
            }
        }
    }
    __syncthreads();

    // ---- Gram (MFMA): G[m][a] = sum_p Y2T[m][p]*Y2T[a][p]; K=128 (col 127=0).
    //      Wave wv (<7) owns m-tile wv. ----
    if (wv < 7) {
        const int krow = (lane >> 4) << 3;
        short8v GB[4];
#pragma unroll
        for (int ks = 0; ks < 4; ++ks) {
            FragU cv; cv.u4 = *(const uint4*)&y2t[lane & 15][ks * 32 + krow];
            GB[ks] = cv.s;
        }
        float* orow = out + (size_t)(b * NC_ + n) * OUTROW + 100;
        const int aa = lane & 15;
        const int m0 = wv * 16 + (lane & 15);
        float4v acc = {0.f, 0.f, 0.f, 0.f};
#pragma unroll
        for (int ks = 0; ks < 4; ++ks) {
            FragU av; av.u4 = *(const uint4*)&y2t[m0][ks * 32 + krow];
            acc = __builtin_amdgcn_mfma_f32_16x16x32_bf16(av.s, GB[ks], acc, 0, 0, 0);
        }
        const int mrow = wv * 16 + ((lane >> 4) << 2);
#pragma unroll
        for (int r = 0; r < 4; ++r) {
            int m = mrow + r;
            if (m < 100) orow[m * 16 + aa] = 2.0f * acc[r];
        }
    }
}

// ---------------------------------------------------------------------------
extern "C" void kernel_launch(void* const* d_in, const int* in_sizes, int n_in,
                              void* d_out, int out_size, void* d_ws, size_t ws_size,
                              hipStream_t stream) {
    (void)in_sizes; (void)n_in; (void)out_size;
    const float* atom_coords   = (const float*)d_in[0];
    const float* charge_coords = (const float*)d_in[1];
    const float* charges       = (const float*)d_in[2];
    const float* eW0 = (const float*)d_in[3];
    const float* eb0 = (const float*)d_in[4];
    const float* eW1 = (const float*)d_in[5];
    const float* eb1 = (const float*)d_in[6];
    const float* eW2 = (const float*)d_in[7];
    const float* eb2 = (const float*)d_in[8];
    const float* fW0 = (const float*)d_in[9];
    const float* fb0 = (const float*)d_in[10];
    const float* fW1 = (const float*)d_in[11];
    const float* fb1 = (const float*)d_in[12];
    const float* fW2 = (const float*)d_in[13];
    const float* fb2 = (const float*)d_in[14];
    const int*   atom_types = (const int*)d_in[15];
    const void*  mask = d_in[16];
    float* out = (float*)d_out;

    // ws layout: [w1bf 147456B][w2bf 516096B][partial B*NC*nchunk*16]
    const size_t W1BF_B = 36 * 64 * 32 * 2;     // 147456
    const size_t W2BF_B = 36 * 112 * 64 * 2;    // 516096
    unsigned short* w1bf = (unsigned short*)d_ws;
    unsigned short* w2bf = (unsigned short*)((char*)d_ws + W1BF_B);
    float4* partial = (float4*)((char*)d_ws + W1BF_B + W2BF_B);

    int nchunk = 128;
    while (nchunk > 1 &&
           W1BF_B + W2BF_B + (size_t)B_ * NC_ * nchunk * 16 > ws_size)
        nchunk >>= 1;

    k_prep<<<72 + B_ * nchunk, 256, 0, stream>>>(
        fW1, fW2, w1bf, w2bf,
        atom_coords, charge_coords, charges, mask, partial, nchunk);
    k_ef<<<B_ * NC_, 512, 0, stream>>>(
        atom_coords, partial, nchunk, atom_types,
        eW0, eb0, eW1, eb1, eW2, eb2,
        fW0, fb0, fb1, fb2, w1bf, w2bf, out);
}